// Round 7
// baseline (146.036 us; speedup 1.0000x reference)
//
#include <hip/hip_runtime.h>
#include <hip/hip_bf16.h>

typedef __attribute__((ext_vector_type(4))) float f32x4;
typedef __attribute__((ext_vector_type(8))) short bf16x8;
typedef __attribute__((ext_vector_type(4))) short short4v;

__device__ __forceinline__ short f2bf(float f) {
  __hip_bfloat16 h = __float2bfloat16(f);
  return __builtin_bit_cast(short, h);
}

// ---------------------------------------------------------------------------
// GEMM view: C[8192 x 512] = A[8192 x 1024] * B[1024 x 512], k = j*4 + kc,
// kc -> x component {0,1,2,4}.
// Bp (d_ws, 1 MB): per-lane MFMA B-frag image Bp[it][cg][w][ft][lane][8sh].
//   Point P = cg*128 + w*32 + (ft&1)*16 + ln.  ft<2 -> c0 row {W0,W1,W2,0};
//   ft>=2 -> c4 row {0,W2,-W1,W0}.  One frag = 1 KB contiguous per wave.
// ---------------------------------------------------------------------------
__global__ __launch_bounds__(256) void ga_prep_B(const float* __restrict__ W,
                                                 short* __restrict__ Bp) {
  const int gid = blockIdx.x * 256 + threadIdx.x;  // 65536 = 32it*2cg*4w*4ft*64l
  const int l  = gid & 63;
  const int ft = (gid >> 6) & 3;
  const int w  = (gid >> 8) & 3;
  const int cg = (gid >> 10) & 1;
  const int it = gid >> 11;
  const int ln = l & 15, q = l >> 4;
  const int hc = ft >> 1;
  const int i  = cg * 128 + w * 32 + (ft & 1) * 16 + ln;
  const int j0 = it * 8 + q * 2;
  const float4* W4 = (const float4*)W;

  bf16x8 o;
#pragma unroll
  for (int jj = 0; jj < 2; ++jj) {
    const float4 wv = W4[((j0 + jj) * 256 + i) * 2];  // W[j][i][0..3]
    if (!hc) {
      o[jj * 4 + 0] = f2bf(wv.x); o[jj * 4 + 1] = f2bf(wv.y);
      o[jj * 4 + 2] = f2bf(wv.z); o[jj * 4 + 3] = 0;
    } else {
      o[jj * 4 + 0] = 0;           o[jj * 4 + 1] = f2bf(wv.z);
      o[jj * 4 + 2] = f2bf(-wv.y); o[jj * 4 + 3] = f2bf(wv.x);
    }
  }
  *(bf16x8*)&Bp[(size_t)gid * 8] = o;
}

// ---------------------------------------------------------------------------
// Main: 512 blocks = 256 row-tiles (M=32) x 2 col-halves (cg: 128 points'
// c0+c4 -> full-32B multivector writes). 256 threads (4 waves), 2 blocks/CU
// (64 KB LDS each). cg-pair XCD swizzle -> x L2 reuse.
// Phase 1: stage ENTIRE A (32 rows x 1024 k bf16, 64 KB) via coalesced
//   float4 streams + shfl comp4 pack; ONE barrier.
// Phase 2: barrier-free K-loop (32 steps): A frags ds_read (prefetch d=1,
//   bank-uniform layout [tau][row][32k]), B frags depth-4 register ring from
//   L2-hot Bp (fine-grained vmcnt, never vmcnt(0)), 8 MFMA/step.
// Phase 3: one barrier, acc->LDS transpose, full-multivector y writes.
// ---------------------------------------------------------------------------
__global__ __launch_bounds__(256, 2) void ga_mv_main(
    const float* __restrict__ x, const short* __restrict__ Bp,
    const float* __restrict__ bias, float* __restrict__ y) {
  __shared__ __align__(16) short A_lds[32768];  // 64 KB: [tau][row][32 k]
  float* c_lds = (float*)A_lds;  // epilogue alias: 32*260*4 = 33,280 B

  const int t = threadIdx.x;
  const int id = blockIdx.x;
  const int g = id & 7;               // XCD slot: ids b, b+8 share rows
  const int cg = (id >> 3) & 1;
  const int bm = (id >> 4) * 8 + g;   // 0..255
  const int R0 = bm * 32;
  const int lane = t & 63, w = t >> 6;
  const int ln = lane & 15, qq = lane >> 4;

  // ---- Phase 1: stage full A tile ----
  // v-step: flat = v*256 + t -> row = v>>1, float4-col c = (v&1)*256 + t.
  // Even c: comps 0-3 of j=c>>1 (owner), odd c: comps 4-7 (donates .x=comp4).
  const float4* x4 = (const float4*)x;
  float4 fr[8];
#pragma unroll
  for (int v = 0; v < 8; ++v)
    fr[v] = x4[(size_t)(R0 + (v >> 1)) * 512 + (v & 1) * 256 + t];
#pragma unroll
  for (int v = 0; v < 64; ++v) {
    const float4 f = fr[v & 7];
    if (v + 8 < 64)
      fr[v & 7] =
          x4[(size_t)(R0 + ((v + 8) >> 1)) * 512 + ((v + 8) & 1) * 256 + t];
    const float c4v = __shfl_xor(f.x, 1, 64);
    if (!(t & 1)) {
      const int row = v >> 1;
      const int j = ((v & 1) * 256 + t) >> 1;
      short4v a;
      a[0] = f2bf(f.x); a[1] = f2bf(f.y); a[2] = f2bf(f.z); a[3] = f2bf(c4v);
      *(short4v*)&A_lds[(j >> 3) * 1024 + row * 32 + (j & 7) * 4] = a;
    }
  }
  __syncthreads();  // barrier #1 (of 3 total)

  // ---- Phase 2: barrier-free K-loop ----
  const short* bpw = Bp + ((size_t)cg * 4 + w) * 2048 + (size_t)lane * 8;
  // it-stride in shorts: 2cg*4w*4ft*64l*8 = 16384; ft-stride: 64*8 = 512
  bf16x8 Bf[4][4];
#pragma unroll
  for (int pb = 0; pb < 4; ++pb)
#pragma unroll
    for (int ft = 0; ft < 4; ++ft)
      Bf[pb][ft] = *(const bf16x8*)(bpw + (size_t)pb * 16384 + ft * 512);

  bf16x8 afr[2][2];
  afr[0][0] = *(const bf16x8*)&A_lds[ln * 32 + qq * 8];
  afr[0][1] = *(const bf16x8*)&A_lds[(16 + ln) * 32 + qq * 8];

  f32x4 acc[8] = {};
#pragma unroll
  for (int it = 0; it < 32; ++it) {
    if (it + 1 < 32) {  // A-frag prefetch: lgkm wait lands next iter
      afr[(it + 1) & 1][0] =
          *(const bf16x8*)&A_lds[(it + 1) * 1024 + ln * 32 + qq * 8];
      afr[(it + 1) & 1][1] =
          *(const bf16x8*)&A_lds[(it + 1) * 1024 + (16 + ln) * 32 + qq * 8];
    }
#pragma unroll
    for (int ft = 0; ft < 4; ++ft) {
      acc[ft] = __builtin_amdgcn_mfma_f32_16x16x32_bf16(
          afr[it & 1][0], Bf[it & 3][ft], acc[ft], 0, 0, 0);
      acc[4 + ft] = __builtin_amdgcn_mfma_f32_16x16x32_bf16(
          afr[it & 1][1], Bf[it & 3][ft], acc[4 + ft], 0, 0, 0);
    }
    if (it + 4 < 32) {  // B ring refill: consumed 4 steps later (vmcnt(N))
#pragma unroll
      for (int ft = 0; ft < 4; ++ft)
        Bf[it & 3][ft] =
            *(const bf16x8*)(bpw + (size_t)(it + 4) * 16384 + ft * 512);
    }
  }

  // ---- Phase 3: epilogue ----
  __syncthreads();  // barrier #2: all waves done reading A_lds (alias!)
  // C/D layout: col = ln, row = qq*4 + r. c col = (ft>>1)*128 + w*32 +
  // (ft&1)*16 + ln (c0 points 0..127 | c4 points 0..127).
#pragma unroll
  for (int mt = 0; mt < 2; ++mt)
#pragma unroll
    for (int ft = 0; ft < 4; ++ft)
#pragma unroll
      for (int r = 0; r < 4; ++r)
        c_lds[(mt * 16 + qq * 4 + r) * 260 + (ft >> 1) * 128 + w * 32 +
              (ft & 1) * 16 + ln] = acc[mt * 4 + ft][r];
  __syncthreads();  // barrier #3

  const int h = t & 1, p = t >> 1;  // point p (0..127), 16B half h
  const float4 bv = ((const float4*)bias)[(cg * 128 + p) * 2 + h];
  float4* y4 = (float4*)y;
#pragma unroll
  for (int row = 0; row < 32; ++row) {
    float4 o = bv;
    o.x += c_lds[row * 260 + h * 128 + p];  // +c0 into comp0 / +c4 into comp4
    y4[((size_t)(R0 + row) * 256 + cg * 128 + p) * 2 + h] = o;  // 4 KB runs
  }
}

extern "C" void kernel_launch(void* const* d_in, const int* in_sizes, int n_in,
                              void* d_out, int out_size, void* d_ws, size_t ws_size,
                              hipStream_t stream) {
  const float* x = (const float*)d_in[0];
  const float* W = (const float*)d_in[1];
  const float* bias = (const float*)d_in[2];
  float* y = (float*)d_out;
  short* Bp = (short*)d_ws;  // 32*2*4*4*64*16 = 1,048,576 B

  ga_prep_B<<<dim3(256), dim3(256), 0, stream>>>(W, Bp);
  ga_mv_main<<<dim3(512), dim3(256), 0, stream>>>(x, Bp, bias, y);
}